// Round 3
// baseline (764.232 us; speedup 1.0000x reference)
//
#include <hip/hip_runtime.h>

// MHABlock (f32 I/O): BN fused into QKV GEMM staging -> {k,v,q} bf16 MFMA GEMMs ->
// focus(q,k) -> linear attention -> dwc residual -> proj GEMM (f32 out).
// Workspace (~44 MB): f32 stats/ksum/kv/bn (2.15MB) | WqkvT bf16 (6.3MB) | WprojT bf16 (2.1MB) | kq bf16 (33.5MB)
// v (bf16, 33.5MB) lives in the low half of d_out (67MB f32) and is dead before proj overwrites it.

#define DEV __device__ __forceinline__

typedef __attribute__((ext_vector_type(8))) short bf16x8;
typedef __attribute__((ext_vector_type(4))) float f32x4;

DEV float bf2f(unsigned short u) {
  union { unsigned int i; float f; } v; v.i = ((unsigned int)u) << 16; return v.f;
}
DEV unsigned short f2bf(float f) {
  union { float f; unsigned int i; } v; v.f = f;
  unsigned int r = v.i + 0x7FFFu + ((v.i >> 16) & 1u);
  return (unsigned short)(r >> 16);
}

// ---------------- zero ----------------
__global__ void zero_f32(float* p, int n) {
  int i = blockIdx.x * 256 + threadIdx.x;
  if (i < n) p[i] = 0.f;
}

// ---------------- BN stats: per-channel sum & sumsq over 16384 rows (x is f32) ----------------
__global__ __launch_bounds__(256) void bn_stats(const float* __restrict__ x,
                                                float* __restrict__ s_sum, float* __restrict__ s_sq) {
  int t = threadIdx.x;
  int c0 = t * 4;
  size_t row0 = (size_t)blockIdx.x * 64;
  float s[4] = {0.f,0.f,0.f,0.f}, q[4] = {0.f,0.f,0.f,0.f};
  for (int r = 0; r < 64; ++r) {
    f32x4 v = *(const f32x4*)&x[(row0 + r) * 1024 + c0];
    #pragma unroll
    for (int i = 0; i < 4; ++i) { float f = v[i]; s[i] += f; q[i] += f * f; }
  }
  #pragma unroll
  for (int i = 0; i < 4; ++i) { atomicAdd(&s_sum[c0 + i], s[i]); atomicAdd(&s_sq[c0 + i], q[i]); }
}

// ---------------- BN finalize + softplus(scale), all f32 params ----------------
__global__ void bn_finalize(const float* __restrict__ s_sum, const float* __restrict__ s_sq,
                            const float* __restrict__ gamma, const float* __restrict__ beta,
                            const float* __restrict__ scalep,
                            float* __restrict__ bn_a, float* __restrict__ bn_b, float* __restrict__ invs) {
  int c = threadIdx.x;
  float mean = s_sum[c] * (1.0f / 16384.0f);
  float var  = s_sq[c] * (1.0f / 16384.0f) - mean * mean;
  float a = gamma[c] * rsqrtf(var + 1e-5f);
  bn_a[c] = a;
  bn_b[c] = beta[c] - mean * a;
  float sv = scalep[c];
  float sp = (sv > 20.f) ? sv : log1pf(expf(sv));
  invs[c] = 1.0f / sp;
}

// ---------------- 64x64 tile transpose, f32 in -> bf16 out, out[n][k] = in[k][n] ----------------
__global__ __launch_bounds__(256) void transpose_f32_bf16(const float* __restrict__ in,
                                                          unsigned short* __restrict__ out,
                                                          int R, int Cc) {
  __shared__ float tile[64 * 65];
  int tx = blockIdx.x * 64, ty = blockIdx.y * 64;
  int t = threadIdx.x;
  {
    int rr = t >> 4, g = t & 15;
    #pragma unroll
    for (int p = 0; p < 4; ++p) {
      int r = p * 16 + rr;
      f32x4 v = *(const f32x4*)&in[(size_t)(ty + r) * Cc + tx + g * 4];
      #pragma unroll
      for (int i = 0; i < 4; ++i) tile[r * 65 + g * 4 + i] = v[i];
    }
  }
  __syncthreads();
  {
    int rr = t >> 3, g = t & 7;
    #pragma unroll
    for (int p = 0; p < 2; ++p) {
      int nl = p * 32 + rr;
      uint4 v; unsigned short* u = (unsigned short*)&v;
      #pragma unroll
      for (int j = 0; j < 8; ++j) u[j] = f2bf(tile[(g * 8 + j) * 65 + nl]);
      *(uint4*)&out[(size_t)(tx + nl) * R + ty + g * 8] = v;
    }
  }
}

// ---------------- MFMA GEMM (QKV): C_bf16[M,N] = BN(A_f32)[M,K] * Bt_bf16[N,K]^T + bias ----------------
// 128x128 block tile, BK=64, 4 waves (2x2 of 64x64), 16x16x32 MFMA, XOR-swizzled LDS.
__global__ __launch_bounds__(256) void gemm_qkv(const float* __restrict__ A,
                                                const unsigned short* __restrict__ Bt,
                                                const float* __restrict__ bias,
                                                const float* __restrict__ bn_a,
                                                const float* __restrict__ bn_b,
                                                unsigned short* __restrict__ C,
                                                int M, int N, int K) {
  __shared__ __align__(16) unsigned short As[128 * 64];
  __shared__ __align__(16) unsigned short Bs[128 * 64];
  int t = threadIdx.x;
  int n0 = blockIdx.x * 128, m0 = blockIdx.y * 128;
  int wid = t >> 6, lane = t & 63;
  int l16 = lane & 15, qd = lane >> 4;
  int wm = (wid & 1) * 64, wn = (wid >> 1) * 64;
  int rS = t >> 3, gS = t & 7;   // staging: 32 rows/pass, 8 granules of (8 elems)

  const f32x4 zero4 = {0.f, 0.f, 0.f, 0.f};
  f32x4 acc[4][4];
  #pragma unroll
  for (int i = 0; i < 4; ++i)
    #pragma unroll
    for (int j = 0; j < 4; ++j) acc[i][j] = zero4;

  for (int k0 = 0; k0 < K; k0 += 64) {
    __syncthreads();
    int cb = k0 + gS * 8;
    float ba[8], bb[8];
    #pragma unroll
    for (int i = 0; i < 8; ++i) { ba[i] = bn_a[cb + i]; bb[i] = bn_b[cb + i]; }
    #pragma unroll
    for (int p = 0; p < 4; ++p) {
      int r = p * 32 + rS;
      const float* ap = &A[(size_t)(m0 + r) * K + cb];
      f32x4 a0 = *(const f32x4*)ap;
      f32x4 a1 = *(const f32x4*)(ap + 4);
      uint4 va; unsigned short* ua = (unsigned short*)&va;
      #pragma unroll
      for (int i = 0; i < 4; ++i) ua[i] = f2bf(ba[i] * a0[i] + bb[i]);
      #pragma unroll
      for (int i = 0; i < 4; ++i) ua[4 + i] = f2bf(ba[4 + i] * a1[i] + bb[4 + i]);
      uint4 vb = *(const uint4*)&Bt[(size_t)(n0 + r) * K + cb];
      int sw = (gS ^ (r & 7)) * 8;   // XOR swizzle
      *(uint4*)&As[r * 64 + sw] = va;
      *(uint4*)&Bs[r * 64 + sw] = vb;
    }
    __syncthreads();
    #pragma unroll
    for (int ks = 0; ks < 2; ++ks) {
      bf16x8 af[4], bfr[4];
      #pragma unroll
      for (int i = 0; i < 4; ++i) {
        int ml = wm + i * 16 + l16;
        af[i] = *(const bf16x8*)&As[ml * 64 + (((ks * 4 + qd) ^ (ml & 7)) * 8)];
        int nl = wn + i * 16 + l16;
        bfr[i] = *(const bf16x8*)&Bs[nl * 64 + (((ks * 4 + qd) ^ (nl & 7)) * 8)];
      }
      #pragma unroll
      for (int i = 0; i < 4; ++i)
        #pragma unroll
        for (int j = 0; j < 4; ++j)
          acc[i][j] = __builtin_amdgcn_mfma_f32_16x16x32_bf16(af[i], bfr[j], acc[i][j], 0, 0, 0);
    }
  }
  // epilogue: row = quad*4+reg, col = lane&15
  #pragma unroll
  for (int i = 0; i < 4; ++i) {
    int row = m0 + wm + i * 16 + qd * 4;
    #pragma unroll
    for (int j = 0; j < 4; ++j) {
      int col = n0 + wn + j * 16 + l16;
      float bv = bias[col];
      #pragma unroll
      for (int rr = 0; rr < 4; ++rr)
        C[(size_t)(row + rr) * N + col] = f2bf(acc[i][j][rr] + bv);
    }
  }
}

// ---------------- MFMA GEMM (proj): C_f32[M,N] = A_bf16[M,K] * Bt_bf16[N,K]^T + bias ----------------
__global__ __launch_bounds__(256) void gemm_proj(const unsigned short* __restrict__ A,
                                                 const unsigned short* __restrict__ Bt,
                                                 const float* __restrict__ bias,
                                                 float* __restrict__ C,
                                                 int M, int N, int K) {
  __shared__ __align__(16) unsigned short As[128 * 64];
  __shared__ __align__(16) unsigned short Bs[128 * 64];
  int t = threadIdx.x;
  int n0 = blockIdx.x * 128, m0 = blockIdx.y * 128;
  int wid = t >> 6, lane = t & 63;
  int l16 = lane & 15, qd = lane >> 4;
  int wm = (wid & 1) * 64, wn = (wid >> 1) * 64;
  int rS = t >> 3, gS = t & 7;

  const f32x4 zero4 = {0.f, 0.f, 0.f, 0.f};
  f32x4 acc[4][4];
  #pragma unroll
  for (int i = 0; i < 4; ++i)
    #pragma unroll
    for (int j = 0; j < 4; ++j) acc[i][j] = zero4;

  for (int k0 = 0; k0 < K; k0 += 64) {
    __syncthreads();
    #pragma unroll
    for (int p = 0; p < 4; ++p) {
      int r = p * 32 + rS;
      uint4 va = *(const uint4*)&A[(size_t)(m0 + r) * K + k0 + gS * 8];
      uint4 vb = *(const uint4*)&Bt[(size_t)(n0 + r) * K + k0 + gS * 8];
      int sw = (gS ^ (r & 7)) * 8;
      *(uint4*)&As[r * 64 + sw] = va;
      *(uint4*)&Bs[r * 64 + sw] = vb;
    }
    __syncthreads();
    #pragma unroll
    for (int ks = 0; ks < 2; ++ks) {
      bf16x8 af[4], bfr[4];
      #pragma unroll
      for (int i = 0; i < 4; ++i) {
        int ml = wm + i * 16 + l16;
        af[i] = *(const bf16x8*)&As[ml * 64 + (((ks * 4 + qd) ^ (ml & 7)) * 8)];
        int nl = wn + i * 16 + l16;
        bfr[i] = *(const bf16x8*)&Bs[nl * 64 + (((ks * 4 + qd) ^ (nl & 7)) * 8)];
      }
      #pragma unroll
      for (int i = 0; i < 4; ++i)
        #pragma unroll
        for (int j = 0; j < 4; ++j)
          acc[i][j] = __builtin_amdgcn_mfma_f32_16x16x32_bf16(af[i], bfr[j], acc[i][j], 0, 0, 0);
    }
  }
  #pragma unroll
  for (int i = 0; i < 4; ++i) {
    int row = m0 + wm + i * 16 + qd * 4;
    #pragma unroll
    for (int j = 0; j < 4; ++j) {
      int col = n0 + wn + j * 16 + l16;
      float bv = bias[col];
      #pragma unroll
      for (int rr = 0; rr < 4; ++rr)
        C[(size_t)(row + rr) * N + col] = acc[i][j][rr] + bv;
    }
  }
}

// ---------------- focus (in-place on a 16384x1024 bf16 buffer) ----------------
__global__ __launch_bounds__(256) void focus_kernel(unsigned short* __restrict__ buf,
                                                    const float* __restrict__ invs) {
  int row = blockIdx.x;
  unsigned short* p = buf + (size_t)row * 1024;
  int t = threadIdx.x;
  int c0 = t * 4;
  uint2 v = *(uint2*)&p[c0];
  unsigned short* u = (unsigned short*)&v;
  float ti[4]; float s2 = 0.f, s6 = 0.f;
  #pragma unroll
  for (int i = 0; i < 4; ++i) {
    float f = bf2f(u[i]);
    f = fmaxf(f, 0.f) + 1e-6f;
    f *= invs[c0 + i];
    ti[i] = f;
    float f2 = f * f;
    s2 += f2; s6 += f2 * f2 * f2;
  }
  #pragma unroll
  for (int off = 32; off > 0; off >>= 1) { s2 += __shfl_down(s2, off); s6 += __shfl_down(s6, off); }
  __shared__ float red[8]; __shared__ float bc;
  int wid = t >> 6, lane = t & 63;
  if (lane == 0) { red[wid] = s2; red[4 + wid] = s6; }
  __syncthreads();
  if (t == 0) {
    float a = red[0] + red[1] + red[2] + red[3];
    float b2 = red[4] + red[5] + red[6] + red[7];
    bc = sqrtf(a / b2);   // nrm / ||t^3||
  }
  __syncthreads();
  float factor = bc;
  #pragma unroll
  for (int i = 0; i < 4; ++i) u[i] = f2bf(ti[i] * ti[i] * ti[i] * factor);
  *(uint2*)&p[c0] = v;
}

// ---------------- attention stats: ksum[bh][d], kv[bh][d][e] (k,v are bf16) ----------------
__global__ __launch_bounds__(256) void attn_stats(const unsigned short* __restrict__ kbuf,
                                                  const unsigned short* __restrict__ vbuf,
                                                  float* __restrict__ ksum, float* __restrict__ kv) {
  int chunk = blockIdx.x, h = blockIdx.y, b = blockIdx.z;
  int bh = b * 16 + h;
  int t = threadIdx.x;
  int d = t >> 2, e0 = (t & 3) * 16;
  __shared__ __align__(16) unsigned short kl[16 * 64];
  __shared__ __align__(16) unsigned short vl[16 * 64];
  float acc[16];
  #pragma unroll
  for (int i = 0; i < 16; ++i) acc[i] = 0.f;
  float ks = 0.f;
  int rs = (t & 127) >> 3, gs = t & 7;
  for (int it = 0; it < 32; ++it) {
    __syncthreads();
    size_t grow = (size_t)b * 2048 + chunk * 512 + it * 16 + rs;
    if (t < 128)
      *(uint4*)&kl[rs * 64 + gs * 8] = *(const uint4*)&kbuf[grow * 1024 + h * 64 + gs * 8];
    else
      *(uint4*)&vl[rs * 64 + gs * 8] = *(const uint4*)&vbuf[grow * 1024 + h * 64 + gs * 8];
    __syncthreads();
    #pragma unroll 4
    for (int r = 0; r < 16; ++r) {
      float kd = bf2f(kl[r * 64 + d]);
      ks += kd;
      uint4 v0 = *(const uint4*)&vl[r * 64 + e0];
      uint4 v1 = *(const uint4*)&vl[r * 64 + e0 + 8];
      const unsigned short* u0 = (const unsigned short*)&v0;
      const unsigned short* u1 = (const unsigned short*)&v1;
      #pragma unroll
      for (int i = 0; i < 8; ++i) { acc[i] += kd * bf2f(u0[i]); acc[8 + i] += kd * bf2f(u1[i]); }
    }
  }
  float* kvp = kv + (size_t)bh * 4096 + d * 64 + e0;
  #pragma unroll
  for (int i = 0; i < 16; ++i) atomicAdd(&kvp[i], acc[i]);
  if ((t & 3) == 0) atomicAdd(&ksum[bh * 64 + d], ks);
}

// ---------------- o = (q @ kv) * z, written IN PLACE over q (bf16) ----------------
__global__ __launch_bounds__(256) void attn_o(unsigned short* qod,
                                              const float* __restrict__ ksum,
                                              const float* __restrict__ kv) {
  int nt = blockIdx.x, h = blockIdx.y, b = blockIdx.z;
  int bh = b * 16 + h;
  int t = threadIdx.x;
  __shared__ __align__(16) float kvl[4096];
  __shared__ float ksl[64];
  __shared__ float ql[128 * 65];
  const float* kvg = kv + (size_t)bh * 4096;
  #pragma unroll
  for (int i = 0; i < 16; ++i) kvl[t + i * 256] = kvg[t + i * 256];
  if (t < 64) ksl[t] = ksum[bh * 64 + t];
  {
    int r = t >> 1, dh = (t & 1) * 32;
    size_t grow = (size_t)b * 2048 + nt * 128 + r;
    const unsigned short* qp = qod + grow * 1024 + h * 64 + dh;
    #pragma unroll
    for (int p2 = 0; p2 < 4; ++p2) {
      uint4 v = *(const uint4*)&qp[p2 * 8];
      const unsigned short* u = (const unsigned short*)&v;
      #pragma unroll
      for (int i = 0; i < 8; ++i) ql[r * 65 + dh + p2 * 8 + i] = bf2f(u[i]);
    }
  }
  __syncthreads();
  int r = t & 127, eh = (t >> 7) * 32;
  float zs = 0.f;
  #pragma unroll 8
  for (int d = 0; d < 64; ++d) zs += ql[r * 65 + d] * ksl[d];
  float z = 1.f / (zs + 1e-6f);
  float acc[32];
  #pragma unroll
  for (int i = 0; i < 32; ++i) acc[i] = 0.f;
  for (int d = 0; d < 64; ++d) {
    float qv = ql[r * 65 + d];
    #pragma unroll
    for (int e4 = 0; e4 < 8; ++e4) {
      f32x4 kvv = *(const f32x4*)&kvl[d * 64 + eh + e4 * 4];
      acc[e4 * 4 + 0] += qv * kvv[0];
      acc[e4 * 4 + 1] += qv * kvv[1];
      acc[e4 * 4 + 2] += qv * kvv[2];
      acc[e4 * 4 + 3] += qv * kvv[3];
    }
  }
  size_t orow = (size_t)b * 2048 + nt * 128 + r;
  unsigned short* op = qod + orow * 1024 + h * 64 + eh;
  #pragma unroll
  for (int p2 = 0; p2 < 4; ++p2) {
    uint4 v; unsigned short* u = (unsigned short*)&v;
    #pragma unroll
    for (int i = 0; i < 8; ++i) u[i] = f2bf(acc[p2 * 8 + i] * z);
    *(uint4*)&op[p2 * 8] = v;
  }
}

// ---------------- depthwise conv on v (+bias) added into od; dwc weights f32 ----------------
__global__ __launch_bounds__(256) void dwc_add(const unsigned short* __restrict__ vbuf,
                                               const float* __restrict__ dwcw,
                                               const float* __restrict__ dwcb,
                                               unsigned short* __restrict__ od) {
  int row = blockIdx.x;
  int b = row >> 11, n = row & 2047;
  int t = threadIdx.x, c0 = t * 4;
  float w[4][5];
  #pragma unroll
  for (int i = 0; i < 4; ++i)
    #pragma unroll
    for (int j = 0; j < 5; ++j) w[i][j] = dwcw[(c0 + i) * 5 + j];
  float s[4] = {0.f,0.f,0.f,0.f};
  #pragma unroll
  for (int j = 0; j < 5; ++j) {
    int nn = n + j - 2;
    if (nn < 0 || nn >= 2048) continue;
    uint2 v = *(const uint2*)&vbuf[((size_t)b * 2048 + nn) * 1024 + c0];
    const unsigned short* u = (const unsigned short*)&v;
    #pragma unroll
    for (int i = 0; i < 4; ++i) s[i] += bf2f(u[i]) * w[i][j];
  }
  size_t o = (size_t)row * 1024 + c0;
  uint2 ov = *(uint2*)&od[o];
  unsigned short* uo = (unsigned short*)&ov;
  #pragma unroll
  for (int i = 0; i < 4; ++i) uo[i] = f2bf(bf2f(uo[i]) + s[i] + dwcb[c0 + i]);
  *(uint2*)&od[o] = ov;
}

extern "C" void kernel_launch(void* const* d_in, const int* in_sizes, int n_in,
                              void* d_out, int out_size, void* d_ws, size_t ws_size,
                              hipStream_t stream) {
  const float* x      = (const float*)d_in[0];
  const float* gamma  = (const float*)d_in[1];
  const float* beta   = (const float*)d_in[2];
  const float* Wqkv   = (const float*)d_in[3];
  const float* bqkv   = (const float*)d_in[4];
  const float* scalep = (const float*)d_in[5];
  const float* dwcw   = (const float*)d_in[6];
  const float* dwcb   = (const float*)d_in[7];
  const float* Wproj  = (const float*)d_in[8];
  const float* bproj  = (const float*)d_in[9];
  float* out = (float*)d_out;

  float* wsf = (float*)d_ws;
  float* s_sum = wsf;                    // 1024
  float* s_sq  = wsf + 1024;             // 1024
  float* ksum  = wsf + 2048;             // 8192
  float* kv    = wsf + 10240;            // 524288
  float* bn_a  = wsf + 534528;           // 1024
  float* bn_b  = wsf + 535552;           // 1024
  float* invs  = wsf + 536576;           // 1024
  unsigned short* wtq = (unsigned short*)(wsf + 537600); // 3072x1024 bf16 (Wqkv^T)
  unsigned short* wtp = wtq + 3145728;                   // 1024x1024 bf16 (Wproj^T)
  unsigned short* kq  = wtp + 1048576;                   // 16384x1024 bf16: k, then q, then o+dwc
  unsigned short* vbf = (unsigned short*)d_out;          // v (bf16) in low half of d_out; dead before proj writes
  // ws total = 2.15 + 6.29 + 2.10 + 33.55 = ~44.1 MB

  zero_f32<<<2088, 256, 0, stream>>>(wsf, 534528);                 // stats + ksum + kv
  bn_stats<<<256, 256, 0, stream>>>(x, s_sum, s_sq);
  bn_finalize<<<1, 1024, 0, stream>>>(s_sum, s_sq, gamma, beta, scalep, bn_a, bn_b, invs);
  transpose_f32_bf16<<<dim3(48, 16), 256, 0, stream>>>(Wqkv, wtq, 1024, 3072);
  transpose_f32_bf16<<<dim3(16, 16), 256, 0, stream>>>(Wproj, wtp, 1024, 1024);

  gemm_qkv<<<dim3(8, 128), 256, 0, stream>>>(x, wtq + 1024 * 1024, bqkv + 1024, bn_a, bn_b, kq, 16384, 1024, 1024);  // k
  focus_kernel<<<16384, 256, 0, stream>>>(kq, invs);                                                                  // focus(k)
  gemm_qkv<<<dim3(8, 128), 256, 0, stream>>>(x, wtq + 2048 * 1024, bqkv + 2048, bn_a, bn_b, vbf, 16384, 1024, 1024); // v
  attn_stats<<<dim3(4, 16, 8), 256, 0, stream>>>(kq, vbf, ksum, kv);
  gemm_qkv<<<dim3(8, 128), 256, 0, stream>>>(x, wtq, bqkv, bn_a, bn_b, kq, 16384, 1024, 1024);                       // q (over k)
  focus_kernel<<<16384, 256, 0, stream>>>(kq, invs);                                                                  // focus(q)
  attn_o<<<dim3(16, 16, 8), 256, 0, stream>>>(kq, ksum, kv);                                                          // o in place
  dwc_add<<<16384, 256, 0, stream>>>(vbf, dwcw, dwcb, kq);                                                            // + dwc
  gemm_proj<<<dim3(8, 128), 256, 0, stream>>>(kq, wtp, bproj, out, 16384, 1024, 1024);                               // proj -> f32 out
}

// Round 4
// 643.547 us; speedup vs baseline: 1.1875x; 1.1875x over previous
//
#include <hip/hip_runtime.h>

// MHABlock (f32 I/O): BN -> xn(bf16) -> {k,v,q} MFMA GEMMs (async LDS staging) ->
// focus(q,k) -> linear attention (register-blocked kv stats + partials-reduce) ->
// dwc residual -> proj GEMM (f32 out).
// ws (~61 MB): f32 stats/ksum/kv/bn | kvpart (8x128x4096 f32) | WqkvT | WprojT | kq
// xn (bf16) and v (bf16) live in the upper/lower halves of d_out (dead before proj writes).

#define DEV __device__ __forceinline__

typedef __attribute__((ext_vector_type(8))) short bf16x8;
typedef __attribute__((ext_vector_type(4))) float f32x4;
typedef unsigned short us;

DEV float bf2f(us u) {
  union { unsigned int i; float f; } v; v.i = ((unsigned int)u) << 16; return v.f;
}
DEV us f2bf(float f) {
  union { float f; unsigned int i; } v; v.f = f;
  unsigned int r = v.i + 0x7FFFu + ((v.i >> 16) & 1u);
  return (us)(r >> 16);
}
// async global->LDS, 16B per lane; LDS dest = wave-uniform base + lane*16
DEV void glds16(const us* g, us* l) {
  __builtin_amdgcn_global_load_lds((const __attribute__((address_space(1))) unsigned int*)g,
                                   (__attribute__((address_space(3))) unsigned int*)l, 16, 0, 0);
}

// ---------------- zero ----------------
__global__ void zero_f32(float* p, int n) {
  int i = blockIdx.x * 256 + threadIdx.x;
  if (i < n) p[i] = 0.f;
}

// ---------------- BN stats ----------------
__global__ __launch_bounds__(256) void bn_stats(const float* __restrict__ x,
                                                float* __restrict__ s_sum, float* __restrict__ s_sq) {
  int t = threadIdx.x;
  int c0 = t * 4;
  size_t row0 = (size_t)blockIdx.x * 64;
  float s[4] = {0.f,0.f,0.f,0.f}, q[4] = {0.f,0.f,0.f,0.f};
  for (int r = 0; r < 64; ++r) {
    f32x4 v = *(const f32x4*)&x[(row0 + r) * 1024 + c0];
    #pragma unroll
    for (int i = 0; i < 4; ++i) { float f = v[i]; s[i] += f; q[i] += f * f; }
  }
  #pragma unroll
  for (int i = 0; i < 4; ++i) { atomicAdd(&s_sum[c0 + i], s[i]); atomicAdd(&s_sq[c0 + i], q[i]); }
}

// ---------------- BN finalize + softplus(scale) ----------------
__global__ void bn_finalize(const float* __restrict__ s_sum, const float* __restrict__ s_sq,
                            const float* __restrict__ gamma, const float* __restrict__ beta,
                            const float* __restrict__ scalep,
                            float* __restrict__ bn_a, float* __restrict__ bn_b, float* __restrict__ invs) {
  int c = threadIdx.x;
  float mean = s_sum[c] * (1.0f / 16384.0f);
  float var  = s_sq[c] * (1.0f / 16384.0f) - mean * mean;
  float a = gamma[c] * rsqrtf(var + 1e-5f);
  bn_a[c] = a;
  bn_b[c] = beta[c] - mean * a;
  float sv = scalep[c];
  float sp = (sv > 20.f) ? sv : log1pf(expf(sv));
  invs[c] = 1.0f / sp;
}

// ---------------- xn = BN(x) as bf16 ----------------
__global__ __launch_bounds__(256) void xn_to_bf16(const float* __restrict__ x,
                                                  const float* __restrict__ bn_a, const float* __restrict__ bn_b,
                                                  us* __restrict__ xn) {
  size_t base = ((size_t)blockIdx.x * 256 + threadIdx.x) * 8;
  int c = (int)(base & 1023);
  f32x4 a0 = *(const f32x4*)&x[base];
  f32x4 a1 = *(const f32x4*)&x[base + 4];
  uint4 o; us* uo = (us*)&o;
  #pragma unroll
  for (int i = 0; i < 4; ++i) uo[i] = f2bf(bn_a[c + i] * a0[i] + bn_b[c + i]);
  #pragma unroll
  for (int i = 0; i < 4; ++i) uo[4 + i] = f2bf(bn_a[c + 4 + i] * a1[i] + bn_b[c + 4 + i]);
  *(uint4*)&xn[base] = o;
}

// ---------------- 64x64 transpose f32 -> bf16, out[n][k] = in[k][n] ----------------
__global__ __launch_bounds__(256) void transpose_f32_bf16(const float* __restrict__ in,
                                                          us* __restrict__ out, int R, int Cc) {
  __shared__ float tile[64 * 65];
  int tx = blockIdx.x * 64, ty = blockIdx.y * 64;
  int t = threadIdx.x;
  {
    int rr = t >> 4, g = t & 15;
    #pragma unroll
    for (int p = 0; p < 4; ++p) {
      int r = p * 16 + rr;
      f32x4 v = *(const f32x4*)&in[(size_t)(ty + r) * Cc + tx + g * 4];
      #pragma unroll
      for (int i = 0; i < 4; ++i) tile[r * 65 + g * 4 + i] = v[i];
    }
  }
  __syncthreads();
  {
    int rr = t >> 3, g = t & 7;
    #pragma unroll
    for (int p = 0; p < 2; ++p) {
      int nl = p * 32 + rr;
      uint4 v; us* u = (us*)&v;
      #pragma unroll
      for (int j = 0; j < 8; ++j) u[j] = f2bf(tile[(g * 8 + j) * 65 + nl]);
      *(uint4*)&out[(size_t)(tx + nl) * R + ty + g * 8] = v;
    }
  }
}

// ---------------- MFMA GEMM: C[M,N] = A_bf16[M,K] * Bt_bf16[N,K]^T + bias ----------------
// 128x128 tile, BK=64, 4 waves (2x2 of 64x64), 16x16x32 MFMA.
// Staging via global_load_lds width=16; XOR swizzle applied on the SOURCE address
// (LDS slot (r,s) holds global granule s^(r&7)), so fragment reads stay conflict-free.
template <typename OutT>
__global__ __launch_bounds__(256) void gemm_async(const us* __restrict__ A,
                                                  const us* __restrict__ Bt,
                                                  const float* __restrict__ bias,
                                                  OutT* __restrict__ C,
                                                  int M, int N, int K) {
  __shared__ __align__(16) us As[128 * 64];
  __shared__ __align__(16) us Bs[128 * 64];
  int t = threadIdx.x;
  int n0 = blockIdx.x * 128, m0 = blockIdx.y * 128;
  int wid = t >> 6, lane = t & 63;
  int l16 = lane & 15, qd = lane >> 4;
  int wm = (wid & 1) * 64, wn = (wid >> 1) * 64;
  // async staging addressing: lane -> row-within-8 = lane>>3, source granule g = (lane&7)^(lane>>3)
  int rr = lane >> 3, gg = (lane & 7) ^ rr;
  const us* gA = A + (size_t)(m0 + wid * 8 + rr) * K + gg * 8;
  const us* gB = Bt + (size_t)(n0 + wid * 8 + rr) * K + gg * 8;
  us* lA = &As[(wid * 8) * 64];
  us* lB = &Bs[(wid * 8) * 64];

  const f32x4 zero4 = {0.f, 0.f, 0.f, 0.f};
  f32x4 acc[4][4];
  #pragma unroll
  for (int i = 0; i < 4; ++i)
    #pragma unroll
    for (int j = 0; j < 4; ++j) acc[i][j] = zero4;

  for (int k0 = 0; k0 < K; k0 += 64) {
    __syncthreads();
    #pragma unroll
    for (int p = 0; p < 4; ++p) {
      glds16(gA + (size_t)p * 32 * K, lA + p * 32 * 64);
      glds16(gB + (size_t)p * 32 * K, lB + p * 32 * 64);
    }
    gA += 64; gB += 64;
    __syncthreads();   // compiler drains vmcnt(0) before s_barrier -> staged data visible
    #pragma unroll
    for (int ks = 0; ks < 2; ++ks) {
      bf16x8 af[4], bfr[4];
      #pragma unroll
      for (int i = 0; i < 4; ++i) {
        int ml = wm + i * 16 + l16;
        af[i] = *(const bf16x8*)&As[ml * 64 + (((ks * 4 + qd) ^ (ml & 7)) * 8)];
        int nl = wn + i * 16 + l16;
        bfr[i] = *(const bf16x8*)&Bs[nl * 64 + (((ks * 4 + qd) ^ (nl & 7)) * 8)];
      }
      #pragma unroll
      for (int i = 0; i < 4; ++i)
        #pragma unroll
        for (int j = 0; j < 4; ++j)
          acc[i][j] = __builtin_amdgcn_mfma_f32_16x16x32_bf16(af[i], bfr[j], acc[i][j], 0, 0, 0);
    }
  }
  // epilogue: row = quad*4+reg, col = lane&15
  #pragma unroll
  for (int i = 0; i < 4; ++i) {
    int row = m0 + wm + i * 16 + qd * 4;
    #pragma unroll
    for (int j = 0; j < 4; ++j) {
      int col = n0 + wn + j * 16 + l16;
      float bv = bias[col];
      #pragma unroll
      for (int rrr = 0; rrr < 4; ++rrr) {
        float val = acc[i][j][rrr] + bv;
        if constexpr (sizeof(OutT) == 2)
          ((us*)C)[(size_t)(row + rrr) * N + col] = f2bf(val);
        else
          ((float*)C)[(size_t)(row + rrr) * N + col] = val;
      }
    }
  }
}

// ---------------- focus (in-place on 16384x1024 bf16) ----------------
__global__ __launch_bounds__(256) void focus_kernel(us* __restrict__ buf,
                                                    const float* __restrict__ invs) {
  int row = blockIdx.x;
  us* p = buf + (size_t)row * 1024;
  int t = threadIdx.x;
  int c0 = t * 4;
  uint2 v = *(uint2*)&p[c0];
  us* u = (us*)&v;
  float ti[4]; float s2 = 0.f, s6 = 0.f;
  #pragma unroll
  for (int i = 0; i < 4; ++i) {
    float f = bf2f(u[i]);
    f = fmaxf(f, 0.f) + 1e-6f;
    f *= invs[c0 + i];
    ti[i] = f;
    float f2 = f * f;
    s2 += f2; s6 += f2 * f2 * f2;
  }
  #pragma unroll
  for (int off = 32; off > 0; off >>= 1) { s2 += __shfl_down(s2, off); s6 += __shfl_down(s6, off); }
  __shared__ float red[8]; __shared__ float bc;
  int wid = t >> 6, lane = t & 63;
  if (lane == 0) { red[wid] = s2; red[4 + wid] = s6; }
  __syncthreads();
  if (t == 0) {
    float a = red[0] + red[1] + red[2] + red[3];
    float b2 = red[4] + red[5] + red[6] + red[7];
    bc = sqrtf(a / b2);
  }
  __syncthreads();
  float factor = bc;
  #pragma unroll
  for (int i = 0; i < 4; ++i) u[i] = f2bf(ti[i] * ti[i] * ti[i] * factor);
  *(uint2*)&p[c0] = v;
}

// ---------------- attn stats v2: register-blocked kv outer product ----------------
// grid (8,16,8): 256-row chunk, head, batch. Lane = 8x8 (d-group, e-group) tile;
// waves split rows. Per row: 4 ds_read_b128 feed 64 FMA (VALU-bound by design).
// Block partial kv -> kvpart[cx][bh][64][64] (non-atomic); ksum via LDS reduce + 64 atomics.
__global__ __launch_bounds__(256) void attn_stats2(const us* __restrict__ kbuf,
                                                   const us* __restrict__ vbuf,
                                                   float* __restrict__ ksum,
                                                   float* __restrict__ kvpart) {
  int cx = blockIdx.x, h = blockIdx.y, b = blockIdx.z, bh = b * 16 + h;
  int t = threadIdx.x, w = t >> 6, ln = t & 63;
  int dg = ln >> 3, eg = ln & 7;
  __shared__ float kl[32 * 64];   // 8 KB
  __shared__ float vl[32 * 64];   // 8 KB
  __shared__ float red[4096];     // 16 KB
  __shared__ float ksred[64];
  #pragma unroll
  for (int i = 0; i < 16; ++i) red[t + i * 256] = 0.f;
  if (t < 64) ksred[t] = 0.f;

  float acc[8][8];
  #pragma unroll
  for (int j = 0; j < 8; ++j)
    #pragma unroll
    for (int i = 0; i < 8; ++i) acc[j][i] = 0.f;
  float ks[8] = {0.f,0.f,0.f,0.f,0.f,0.f,0.f,0.f};

  int sr = t >> 3, scg = (t & 7) * 8;
  for (int st = 0; st < 8; ++st) {
    __syncthreads();
    size_t grow = ((size_t)b * 2048 + cx * 256 + st * 32 + sr) * 1024 + h * 64 + scg;
    uint4 kk = *(const uint4*)&kbuf[grow];
    uint4 vv = *(const uint4*)&vbuf[grow];
    us* pk = (us*)&kk; us* pv = (us*)&vv;
    #pragma unroll
    for (int i = 0; i < 8; ++i) { kl[sr * 64 + scg + i] = bf2f(pk[i]); vl[sr * 64 + scg + i] = bf2f(pv[i]); }
    __syncthreads();
    for (int r = w; r < 32; r += 4) {
      const float* krow = &kl[r * 64 + dg * 8];
      const float* vrow = &vl[r * 64 + eg * 8];
      f32x4 ka = *(const f32x4*)krow, kb2 = *(const f32x4*)(krow + 4);
      f32x4 va = *(const f32x4*)vrow, vb2 = *(const f32x4*)(vrow + 4);
      float kv8[8] = {ka[0],ka[1],ka[2],ka[3],kb2[0],kb2[1],kb2[2],kb2[3]};
      float vv8[8] = {va[0],va[1],va[2],va[3],vb2[0],vb2[1],vb2[2],vb2[3]};
      #pragma unroll
      for (int j = 0; j < 8; ++j) {
        ks[j] += kv8[j];
        #pragma unroll
        for (int i = 0; i < 8; ++i) acc[j][i] += kv8[j] * vv8[i];
      }
    }
  }
  // ksum: lanes with same (w,dg) hold identical ks -> only eg==0 contributes
  if (eg == 0) {
    #pragma unroll
    for (int j = 0; j < 8; ++j) atomicAdd(&ksred[dg * 8 + j], ks[j]);
  }
  __syncthreads();
  // cross-wave kv reduce via LDS f32 atomics
  #pragma unroll
  for (int j = 0; j < 8; ++j)
    #pragma unroll
    for (int i = 0; i < 8; ++i)
      atomicAdd(&red[(dg * 8 + j) * 64 + eg * 8 + i], acc[j][i]);
  __syncthreads();
  float* pp = kvpart + ((size_t)cx * 128 + bh) * 4096;
  #pragma unroll
  for (int i = 0; i < 16; ++i) pp[t + i * 256] = red[t + i * 256];
  if (t < 64) atomicAdd(&ksum[bh * 64 + t], ksred[t]);
}

// ---------------- kv = sum over 8 chunk partials ----------------
__global__ __launch_bounds__(256) void kv_reduce(const float* __restrict__ part, float* __restrict__ kv) {
  int bh = blockIdx.y;
  int i = blockIdx.x * 256 + threadIdx.x;
  float s = 0.f;
  #pragma unroll
  for (int c = 0; c < 8; ++c) s += part[((size_t)c * 128 + bh) * 4096 + i];
  kv[(size_t)bh * 4096 + i] = s;
}

// ---------------- o = (q @ kv) * z, in place over q (bf16) ----------------
__global__ __launch_bounds__(256) void attn_o(us* qod,
                                              const float* __restrict__ ksum,
                                              const float* __restrict__ kv) {
  int nt = blockIdx.x, h = blockIdx.y, b = blockIdx.z;
  int bh = b * 16 + h;
  int t = threadIdx.x;
  __shared__ __align__(16) float kvl[4096];
  __shared__ float ksl[64];
  __shared__ float ql[128 * 65];
  const float* kvg = kv + (size_t)bh * 4096;
  #pragma unroll
  for (int i = 0; i < 16; ++i) kvl[t + i * 256] = kvg[t + i * 256];
  if (t < 64) ksl[t] = ksum[bh * 64 + t];
  {
    int r = t >> 1, dh = (t & 1) * 32;
    size_t grow = (size_t)b * 2048 + nt * 128 + r;
    const us* qp = qod + grow * 1024 + h * 64 + dh;
    #pragma unroll
    for (int p2 = 0; p2 < 4; ++p2) {
      uint4 v = *(const uint4*)&qp[p2 * 8];
      const us* u = (const us*)&v;
      #pragma unroll
      for (int i = 0; i < 8; ++i) ql[r * 65 + dh + p2 * 8 + i] = bf2f(u[i]);
    }
  }
  __syncthreads();
  int r = t & 127, eh = (t >> 7) * 32;
  float zs = 0.f;
  #pragma unroll 8
  for (int d = 0; d < 64; ++d) zs += ql[r * 65 + d] * ksl[d];
  float z = 1.f / (zs + 1e-6f);
  float acc[32];
  #pragma unroll
  for (int i = 0; i < 32; ++i) acc[i] = 0.f;
  for (int d = 0; d < 64; ++d) {
    float qv = ql[r * 65 + d];
    #pragma unroll
    for (int e4 = 0; e4 < 8; ++e4) {
      f32x4 kvv = *(const f32x4*)&kvl[d * 64 + eh + e4 * 4];
      acc[e4 * 4 + 0] += qv * kvv[0];
      acc[e4 * 4 + 1] += qv * kvv[1];
      acc[e4 * 4 + 2] += qv * kvv[2];
      acc[e4 * 4 + 3] += qv * kvv[3];
    }
  }
  size_t orow = (size_t)b * 2048 + nt * 128 + r;
  us* op = qod + orow * 1024 + h * 64 + eh;
  #pragma unroll
  for (int p2 = 0; p2 < 4; ++p2) {
    uint4 v; us* u = (us*)&v;
    #pragma unroll
    for (int i = 0; i < 8; ++i) u[i] = f2bf(acc[p2 * 8 + i] * z);
    *(uint4*)&op[p2 * 8] = v;
  }
}

// ---------------- depthwise conv residual ----------------
__global__ __launch_bounds__(256) void dwc_add(const us* __restrict__ vbuf,
                                               const float* __restrict__ dwcw,
                                               const float* __restrict__ dwcb,
                                               us* __restrict__ od) {
  int row = blockIdx.x;
  int b = row >> 11, n = row & 2047;
  int t = threadIdx.x, c0 = t * 4;
  float w[4][5];
  #pragma unroll
  for (int i = 0; i < 4; ++i)
    #pragma unroll
    for (int j = 0; j < 5; ++j) w[i][j] = dwcw[(c0 + i) * 5 + j];
  float s[4] = {0.f,0.f,0.f,0.f};
  #pragma unroll
  for (int j = 0; j < 5; ++j) {
    int nn = n + j - 2;
    if (nn < 0 || nn >= 2048) continue;
    uint2 v = *(const uint2*)&vbuf[((size_t)b * 2048 + nn) * 1024 + c0];
    const us* u = (const us*)&v;
    #pragma unroll
    for (int i = 0; i < 4; ++i) s[i] += bf2f(u[i]) * w[i][j];
  }
  size_t o = (size_t)row * 1024 + c0;
  uint2 ov = *(uint2*)&od[o];
  us* uo = (us*)&ov;
  #pragma unroll
  for (int i = 0; i < 4; ++i) uo[i] = f2bf(bf2f(uo[i]) + s[i] + dwcb[c0 + i]);
  *(uint2*)&od[o] = ov;
}

extern "C" void kernel_launch(void* const* d_in, const int* in_sizes, int n_in,
                              void* d_out, int out_size, void* d_ws, size_t ws_size,
                              hipStream_t stream) {
  const float* x      = (const float*)d_in[0];
  const float* gamma  = (const float*)d_in[1];
  const float* beta   = (const float*)d_in[2];
  const float* Wqkv   = (const float*)d_in[3];
  const float* bqkv   = (const float*)d_in[4];
  const float* scalep = (const float*)d_in[5];
  const float* dwcw   = (const float*)d_in[6];
  const float* dwcb   = (const float*)d_in[7];
  const float* Wproj  = (const float*)d_in[8];
  const float* bproj  = (const float*)d_in[9];
  float* out = (float*)d_out;

  float* wsf = (float*)d_ws;
  float* s_sum  = wsf;                   // 1024
  float* s_sq   = wsf + 1024;            // 1024
  float* ksum   = wsf + 2048;            // 8192
  float* kv     = wsf + 10240;           // 524288
  float* bn_a   = wsf + 534528;          // 1024
  float* bn_b   = wsf + 535552;          // 1024
  float* invs   = wsf + 536576;          // 1024
  float* kvpart = wsf + 537600;          // 8*128*4096 = 4194304
  us* wtq = (us*)(wsf + 4731904);        // 3072x1024 bf16
  us* wtp = wtq + 3145728;               // 1024x1024 bf16
  us* kq  = wtp + 1048576;               // 16384x1024 bf16: k, q, o+dwc
  us* vbf = (us*)d_out;                  // v bf16 in low half of d_out
  us* xnb = (us*)d_out + 16777216;       // xn bf16 in high half of d_out
  // ws total ~60.9 MB

  zero_f32<<<40, 256, 0, stream>>>(wsf, 10240);                    // s_sum, s_sq, ksum
  bn_stats<<<256, 256, 0, stream>>>(x, s_sum, s_sq);
  bn_finalize<<<1, 1024, 0, stream>>>(s_sum, s_sq, gamma, beta, scalep, bn_a, bn_b, invs);
  xn_to_bf16<<<8192, 256, 0, stream>>>(x, bn_a, bn_b, xnb);
  transpose_f32_bf16<<<dim3(48, 16), 256, 0, stream>>>(Wqkv, wtq, 1024, 3072);
  transpose_f32_bf16<<<dim3(16, 16), 256, 0, stream>>>(Wproj, wtp, 1024, 1024);

  gemm_async<us><<<dim3(8, 128), 256, 0, stream>>>(xnb, wtq + 1024 * 1024, bqkv + 1024, kq, 16384, 1024, 1024);  // k
  focus_kernel<<<16384, 256, 0, stream>>>(kq, invs);                                                              // focus(k)
  gemm_async<us><<<dim3(8, 128), 256, 0, stream>>>(xnb, wtq + 2048 * 1024, bqkv + 2048, vbf, 16384, 1024, 1024); // v
  attn_stats2<<<dim3(8, 16, 8), 256, 0, stream>>>(kq, vbf, ksum, kvpart);
  kv_reduce<<<dim3(16, 128), 256, 0, stream>>>(kvpart, kv);
  gemm_async<us><<<dim3(8, 128), 256, 0, stream>>>(xnb, wtq, bqkv, kq, 16384, 1024, 1024);                       // q (over k)
  focus_kernel<<<16384, 256, 0, stream>>>(kq, invs);                                                              // focus(q)
  attn_o<<<dim3(16, 16, 8), 256, 0, stream>>>(kq, ksum, kv);                                                      // o in place
  dwc_add<<<16384, 256, 0, stream>>>(vbf, dwcw, dwcb, kq);                                                        // + dwc
  gemm_async<float><<<dim3(8, 128), 256, 0, stream>>>(kq, wtp, bproj, out, 16384, 1024, 1024);                   // proj
}

// Round 5
// 470.815 us; speedup vs baseline: 1.6232x; 1.3669x over previous
//
#include <hip/hip_runtime.h>

// MHABlock (f32 I/O): BN -> xn(bf16) -> {k,v,q} MFMA GEMMs (async LDS staging) ->
// focus(q,k) -> linear attention (kv via MFMA K^T·V; o via MFMA Q·kv with fused dwc) ->
// proj GEMM (f32 out).
// ws (~60 MB): f32 stats/ksum/bn | kvpart (8x128x4096 f32) | kvT bf16 | WqkvT | WprojT | kq
// xn (bf16) and v (bf16) live in the upper/lower halves of d_out (dead before proj writes).

#define DEV __device__ __forceinline__

typedef __attribute__((ext_vector_type(8))) short bf16x8;
typedef __attribute__((ext_vector_type(4))) float f32x4;
typedef unsigned short us;

DEV float bf2f(us u) {
  union { unsigned int i; float f; } v; v.i = ((unsigned int)u) << 16; return v.f;
}
DEV us f2bf(float f) {
  union { float f; unsigned int i; } v; v.f = f;
  unsigned int r = v.i + 0x7FFFu + ((v.i >> 16) & 1u);
  return (us)(r >> 16);
}
DEV void glds16(const us* g, us* l) {
  __builtin_amdgcn_global_load_lds((const __attribute__((address_space(1))) unsigned int*)g,
                                   (__attribute__((address_space(3))) unsigned int*)l, 16, 0, 0);
}

// ---------------- zero ----------------
__global__ void zero_f32(float* p, int n) {
  int i = blockIdx.x * 256 + threadIdx.x;
  if (i < n) p[i] = 0.f;
}

// ---------------- BN stats ----------------
__global__ __launch_bounds__(256) void bn_stats(const float* __restrict__ x,
                                                float* __restrict__ s_sum, float* __restrict__ s_sq) {
  int t = threadIdx.x;
  int c0 = t * 4;
  size_t row0 = (size_t)blockIdx.x * 64;
  float s[4] = {0.f,0.f,0.f,0.f}, q[4] = {0.f,0.f,0.f,0.f};
  for (int r = 0; r < 64; ++r) {
    f32x4 v = *(const f32x4*)&x[(row0 + r) * 1024 + c0];
    #pragma unroll
    for (int i = 0; i < 4; ++i) { float f = v[i]; s[i] += f; q[i] += f * f; }
  }
  #pragma unroll
  for (int i = 0; i < 4; ++i) { atomicAdd(&s_sum[c0 + i], s[i]); atomicAdd(&s_sq[c0 + i], q[i]); }
}

// ---------------- BN finalize + softplus(scale) ----------------
__global__ void bn_finalize(const float* __restrict__ s_sum, const float* __restrict__ s_sq,
                            const float* __restrict__ gamma, const float* __restrict__ beta,
                            const float* __restrict__ scalep,
                            float* __restrict__ bn_a, float* __restrict__ bn_b, float* __restrict__ invs) {
  int c = threadIdx.x;
  float mean = s_sum[c] * (1.0f / 16384.0f);
  float var  = s_sq[c] * (1.0f / 16384.0f) - mean * mean;
  float a = gamma[c] * rsqrtf(var + 1e-5f);
  bn_a[c] = a;
  bn_b[c] = beta[c] - mean * a;
  float sv = scalep[c];
  float sp = (sv > 20.f) ? sv : log1pf(expf(sv));
  invs[c] = 1.0f / sp;
}

// ---------------- xn = BN(x) as bf16 ----------------
__global__ __launch_bounds__(256) void xn_to_bf16(const float* __restrict__ x,
                                                  const float* __restrict__ bn_a, const float* __restrict__ bn_b,
                                                  us* __restrict__ xn) {
  size_t base = ((size_t)blockIdx.x * 256 + threadIdx.x) * 8;
  int c = (int)(base & 1023);
  f32x4 a0 = *(const f32x4*)&x[base];
  f32x4 a1 = *(const f32x4*)&x[base + 4];
  uint4 o; us* uo = (us*)&o;
  #pragma unroll
  for (int i = 0; i < 4; ++i) uo[i] = f2bf(bn_a[c + i] * a0[i] + bn_b[c + i]);
  #pragma unroll
  for (int i = 0; i < 4; ++i) uo[4 + i] = f2bf(bn_a[c + 4 + i] * a1[i] + bn_b[c + 4 + i]);
  *(uint4*)&xn[base] = o;
}

// ---------------- 64x64 transpose f32 -> bf16 ----------------
__global__ __launch_bounds__(256) void transpose_f32_bf16(const float* __restrict__ in,
                                                          us* __restrict__ out, int R, int Cc) {
  __shared__ float tile[64 * 65];
  int tx = blockIdx.x * 64, ty = blockIdx.y * 64;
  int t = threadIdx.x;
  {
    int rr = t >> 4, g = t & 15;
    #pragma unroll
    for (int p = 0; p < 4; ++p) {
      int r = p * 16 + rr;
      f32x4 v = *(const f32x4*)&in[(size_t)(ty + r) * Cc + tx + g * 4];
      #pragma unroll
      for (int i = 0; i < 4; ++i) tile[r * 65 + g * 4 + i] = v[i];
    }
  }
  __syncthreads();
  {
    int rr = t >> 3, g = t & 7;
    #pragma unroll
    for (int p = 0; p < 2; ++p) {
      int nl = p * 32 + rr;
      uint4 v; us* u = (us*)&v;
      #pragma unroll
      for (int j = 0; j < 8; ++j) u[j] = f2bf(tile[(g * 8 + j) * 65 + nl]);
      *(uint4*)&out[(size_t)(tx + nl) * R + ty + g * 8] = v;
    }
  }
}

// ---------------- MFMA GEMM: C[M,N] = A_bf16[M,K] * Bt_bf16[N,K]^T + bias ----------------
template <typename OutT>
__global__ __launch_bounds__(256) void gemm_async(const us* __restrict__ A,
                                                  const us* __restrict__ Bt,
                                                  const float* __restrict__ bias,
                                                  OutT* __restrict__ C,
                                                  int M, int N, int K) {
  __shared__ __align__(16) us As[128 * 64];
  __shared__ __align__(16) us Bs[128 * 64];
  int t = threadIdx.x;
  int n0 = blockIdx.x * 128, m0 = blockIdx.y * 128;
  int wid = t >> 6, lane = t & 63;
  int l16 = lane & 15, qd = lane >> 4;
  int wm = (wid & 1) * 64, wn = (wid >> 1) * 64;
  int rr = lane >> 3, gg = (lane & 7) ^ rr;
  const us* gA = A + (size_t)(m0 + wid * 8 + rr) * K + gg * 8;
  const us* gB = Bt + (size_t)(n0 + wid * 8 + rr) * K + gg * 8;
  us* lA = &As[(wid * 8) * 64];
  us* lB = &Bs[(wid * 8) * 64];

  const f32x4 zero4 = {0.f, 0.f, 0.f, 0.f};
  f32x4 acc[4][4];
  #pragma unroll
  for (int i = 0; i < 4; ++i)
    #pragma unroll
    for (int j = 0; j < 4; ++j) acc[i][j] = zero4;

  for (int k0 = 0; k0 < K; k0 += 64) {
    __syncthreads();
    #pragma unroll
    for (int p = 0; p < 4; ++p) {
      glds16(gA + (size_t)p * 32 * K, lA + p * 32 * 64);
      glds16(gB + (size_t)p * 32 * K, lB + p * 32 * 64);
    }
    gA += 64; gB += 64;
    __syncthreads();
    #pragma unroll
    for (int ks = 0; ks < 2; ++ks) {
      bf16x8 af[4], bfr[4];
      #pragma unroll
      for (int i = 0; i < 4; ++i) {
        int ml = wm + i * 16 + l16;
        af[i] = *(const bf16x8*)&As[ml * 64 + (((ks * 4 + qd) ^ (ml & 7)) * 8)];
        int nl = wn + i * 16 + l16;
        bfr[i] = *(const bf16x8*)&Bs[nl * 64 + (((ks * 4 + qd) ^ (nl & 7)) * 8)];
      }
      #pragma unroll
      for (int i = 0; i < 4; ++i)
        #pragma unroll
        for (int j = 0; j < 4; ++j)
          acc[i][j] = __builtin_amdgcn_mfma_f32_16x16x32_bf16(af[i], bfr[j], acc[i][j], 0, 0, 0);
    }
  }
  #pragma unroll
  for (int i = 0; i < 4; ++i) {
    int row = m0 + wm + i * 16 + qd * 4;
    #pragma unroll
    for (int j = 0; j < 4; ++j) {
      int col = n0 + wn + j * 16 + l16;
      float bv = bias[col];
      #pragma unroll
      for (int rrr = 0; rrr < 4; ++rrr) {
        float val = acc[i][j][rrr] + bv;
        if constexpr (sizeof(OutT) == 2)
          ((us*)C)[(size_t)(row + rrr) * N + col] = f2bf(val);
        else
          ((float*)C)[(size_t)(row + rrr) * N + col] = val;
      }
    }
  }
}

// ---------------- focus (in-place on 16384x1024 bf16) ----------------
__global__ __launch_bounds__(256) void focus_kernel(us* __restrict__ buf,
                                                    const float* __restrict__ invs) {
  int row = blockIdx.x;
  us* p = buf + (size_t)row * 1024;
  int t = threadIdx.x;
  int c0 = t * 4;
  uint2 v = *(uint2*)&p[c0];
  us* u = (us*)&v;
  float ti[4]; float s2 = 0.f, s6 = 0.f;
  #pragma unroll
  for (int i = 0; i < 4; ++i) {
    float f = bf2f(u[i]);
    f = fmaxf(f, 0.f) + 1e-6f;
    f *= invs[c0 + i];
    ti[i] = f;
    float f2 = f * f;
    s2 += f2; s6 += f2 * f2 * f2;
  }
  #pragma unroll
  for (int off = 32; off > 0; off >>= 1) { s2 += __shfl_down(s2, off); s6 += __shfl_down(s6, off); }
  __shared__ float red[8]; __shared__ float bc;
  int wid = t >> 6, lane = t & 63;
  if (lane == 0) { red[wid] = s2; red[4 + wid] = s6; }
  __syncthreads();
  if (t == 0) {
    float a = red[0] + red[1] + red[2] + red[3];
    float b2 = red[4] + red[5] + red[6] + red[7];
    bc = sqrtf(a / b2);
  }
  __syncthreads();
  float factor = bc;
  #pragma unroll
  for (int i = 0; i < 4; ++i) u[i] = f2bf(ti[i] * ti[i] * ti[i] * factor);
  *(uint2*)&p[c0] = v;
}

// ---------------- attn stats v3: kv = K^T·V via MFMA ----------------
// grid (8,16,8): 256-row chunk, head, batch. LDS holds transposed 64x64 k/v tiles
// (pad 80, pair-packed ds_write_b32 staging = conflict-free). 4 waves own 2x2 of the
// 4x4 16x16 output tiles. Partials (non-atomic) -> kvpart; ksum via wave0 + atomics.
__global__ __launch_bounds__(256) void attn_stats3(const us* __restrict__ kbuf,
                                                   const us* __restrict__ vbuf,
                                                   float* __restrict__ ksum,
                                                   float* __restrict__ kvpart) {
  int cx = blockIdx.x, h = blockIdx.y, b = blockIdx.z, bh = b * 16 + h;
  int t = threadIdx.x, wid = t >> 6, lane = t & 63;
  int l16 = lane & 15, qd = lane >> 4;
  int wm = (wid & 1) * 32, wn = (wid >> 1) * 32;
  __shared__ __align__(16) us kT[64 * 80];
  __shared__ __align__(16) us vT[64 * 80];
  const f32x4 zero4 = {0.f, 0.f, 0.f, 0.f};
  f32x4 acc[2][2];
  #pragma unroll
  for (int i = 0; i < 2; ++i)
    #pragma unroll
    for (int j = 0; j < 2; ++j) acc[i][j] = zero4;
  float ksacc = 0.f;
  int np = (t & 31) * 2, ch0 = (t >> 5) * 8;

  for (int ck = 0; ck < 4; ++ck) {
    __syncthreads();
    size_t base = ((size_t)b * 2048 + cx * 256 + ck * 64 + np) * 1024 + h * 64 + ch0;
    uint4 k0 = *(const uint4*)&kbuf[base];
    uint4 k1 = *(const uint4*)&kbuf[base + 1024];
    uint4 v0 = *(const uint4*)&vbuf[base];
    uint4 v1 = *(const uint4*)&vbuf[base + 1024];
    us* pk0 = (us*)&k0; us* pk1 = (us*)&k1; us* pv0 = (us*)&v0; us* pv1 = (us*)&v1;
    #pragma unroll
    for (int i = 0; i < 8; ++i) {
      unsigned int pk = (unsigned int)pk0[i] | ((unsigned int)pk1[i] << 16);
      unsigned int pv = (unsigned int)pv0[i] | ((unsigned int)pv1[i] << 16);
      *(unsigned int*)&kT[(ch0 + i) * 80 + np] = pk;
      *(unsigned int*)&vT[(ch0 + i) * 80 + np] = pv;
    }
    __syncthreads();
    if (t < 64) {                       // ksum: wave0, d = t
      #pragma unroll
      for (int g = 0; g < 8; ++g) {
        bf16x8 kk = *(const bf16x8*)&kT[t * 80 + g * 8];
        #pragma unroll
        for (int j = 0; j < 8; ++j) ksacc += bf2f(((us*)&kk)[j]);
      }
    }
    #pragma unroll
    for (int ks = 0; ks < 2; ++ks) {
      bf16x8 af[2], bfr[2];
      #pragma unroll
      for (int i = 0; i < 2; ++i) {
        af[i]  = *(const bf16x8*)&kT[(wm + i * 16 + l16) * 80 + ks * 32 + qd * 8];
        bfr[i] = *(const bf16x8*)&vT[(wn + i * 16 + l16) * 80 + ks * 32 + qd * 8];
      }
      #pragma unroll
      for (int i = 0; i < 2; ++i)
        #pragma unroll
        for (int j = 0; j < 2; ++j)
          acc[i][j] = __builtin_amdgcn_mfma_f32_16x16x32_bf16(af[i], bfr[j], acc[i][j], 0, 0, 0);
    }
  }
  float* pp = kvpart + ((size_t)cx * 128 + bh) * 4096;
  #pragma unroll
  for (int i = 0; i < 2; ++i) {
    int d = wm + i * 16 + qd * 4;
    #pragma unroll
    for (int j = 0; j < 2; ++j) {
      int e = wn + j * 16 + l16;
      #pragma unroll
      for (int r = 0; r < 4; ++r) pp[(d + r) * 64 + e] = acc[i][j][r];
    }
  }
  if (t < 64) atomicAdd(&ksum[bh * 64 + t], ksacc);
}

// ---------------- kv partial reduce -> kvT (bf16, [bh][e][d]) ----------------
__global__ __launch_bounds__(256) void kv_reduce(const float* __restrict__ part, us* __restrict__ kvT) {
  int bh = blockIdx.x;
  int t = threadIdx.x;
  __shared__ float kvl[4096];
  #pragma unroll
  for (int p = 0; p < 16; ++p) {
    int i = p * 256 + t;
    float s = 0.f;
    #pragma unroll
    for (int c = 0; c < 8; ++c) s += part[((size_t)c * 128 + bh) * 4096 + i];
    kvl[i] = s;
  }
  __syncthreads();
  #pragma unroll
  for (int p = 0; p < 2; ++p) {
    int idx = p * 256 + t;
    int e = idx >> 3, d0 = (idx & 7) * 8;
    uint4 o; us* uo = (us*)&o;
    #pragma unroll
    for (int i = 0; i < 8; ++i) uo[i] = f2bf(kvl[(d0 + i) * 64 + e]);
    *(uint4*)&kvT[(size_t)bh * 4096 + e * 64 + d0] = o;
  }
}

// ---------------- attn_o v2: o = (Q·kv)·z + dwc(v) + dwc_b, MFMA, in place over q ----------------
// grid (16,16,8): 128-row tile, head, batch. qs/bs XOR-swizzled (proven gemm layout);
// vs holds the v tile with +-2 halo for the fused depthwise conv.
__global__ __launch_bounds__(256) void attn_o2(us* __restrict__ qod,
                                               const us* __restrict__ vbuf,
                                               const float* __restrict__ ksum,
                                               const us* __restrict__ kvT,
                                               const float* __restrict__ dwcw,
                                               const float* __restrict__ dwcb) {
  int nt = blockIdx.x, h = blockIdx.y, b = blockIdx.z, bh = b * 16 + h;
  int t = threadIdx.x, wid = t >> 6, lane = t & 63;
  int l16 = lane & 15, qd = lane >> 4;
  __shared__ __align__(16) us qs[128 * 64];
  __shared__ __align__(16) us bs[64 * 64];
  __shared__ __align__(16) us vs[132 * 64];
  __shared__ float zl[128];
  __shared__ float ksl[64];
  __shared__ float wl[64 * 5];
  __shared__ float bl[64];
  int rS = t >> 3, gS = t & 7;
  size_t qbase = ((size_t)b * 2048 + nt * 128) * 1024 + h * 64;
  #pragma unroll
  for (int p = 0; p < 4; ++p) {        // q tile, swizzled
    int r = p * 32 + rS;
    uint4 v = *(const uint4*)&qod[qbase + (size_t)r * 1024 + gS * 8];
    *(uint4*)&qs[r * 64 + ((gS ^ (r & 7)) * 8)] = v;
  }
  #pragma unroll
  for (int p = 0; p < 2; ++p) {        // kvT tile, swizzled
    int r = p * 32 + rS;
    uint4 v = *(const uint4*)&kvT[(size_t)bh * 4096 + r * 64 + gS * 8];
    *(uint4*)&bs[r * 64 + ((gS ^ (r & 7)) * 8)] = v;
  }
  int n0 = nt * 128;
  #pragma unroll
  for (int p = 0; p < 5; ++p) {        // v tile with halo
    int idx = p * 256 + t;
    if (idx < 1056) {
      int r = idx >> 3, g = idx & 7;
      int n = n0 - 2 + r;
      uint4 v = make_uint4(0, 0, 0, 0);
      if (n >= 0 && n < 2048)
        v = *(const uint4*)&vbuf[((size_t)b * 2048 + n) * 1024 + h * 64 + g * 8];
      *(uint4*)&vs[r * 64 + g * 8] = v;
    }
  }
  if (t < 64) {
    ksl[t] = ksum[bh * 64 + t];
    bl[t] = dwcb[h * 64 + t];
    #pragma unroll
    for (int j = 0; j < 5; ++j) wl[t * 5 + j] = dwcw[(h * 64 + t) * 5 + j];
  }
  __syncthreads();
  if (t < 128) {                       // z per row
    float zs = 0.f;
    #pragma unroll
    for (int g = 0; g < 8; ++g) {
      bf16x8 qv = *(const bf16x8*)&qs[t * 64 + ((g ^ (t & 7)) * 8)];
      #pragma unroll
      for (int j = 0; j < 8; ++j) zs += bf2f(((us*)&qv)[j]) * ksl[g * 8 + j];
    }
    zl[t] = 1.f / (zs + 1e-6f);
  }
  __syncthreads();
  const f32x4 zero4 = {0.f, 0.f, 0.f, 0.f};
  f32x4 acc[2][4];
  #pragma unroll
  for (int i = 0; i < 2; ++i)
    #pragma unroll
    for (int j = 0; j < 4; ++j) acc[i][j] = zero4;
  #pragma unroll
  for (int ks = 0; ks < 2; ++ks) {
    bf16x8 af[2], bfr[4];
    #pragma unroll
    for (int i = 0; i < 2; ++i) {
      int ml = (wid * 2 + i) * 16 + l16;
      af[i] = *(const bf16x8*)&qs[ml * 64 + (((ks * 4 + qd) ^ (ml & 7)) * 8)];
    }
    #pragma unroll
    for (int j = 0; j < 4; ++j) {
      int nl = j * 16 + l16;
      bfr[j] = *(const bf16x8*)&bs[nl * 64 + (((ks * 4 + qd) ^ (nl & 7)) * 8)];
    }
    #pragma unroll
    for (int i = 0; i < 2; ++i)
      #pragma unroll
      for (int j = 0; j < 4; ++j)
        acc[i][j] = __builtin_amdgcn_mfma_f32_16x16x32_bf16(af[i], bfr[j], acc[i][j], 0, 0, 0);
  }
  // epilogue: o*z + dwc + bias, write bf16 in place
  #pragma unroll
  for (int i = 0; i < 2; ++i) {
    int rl0 = (wid * 2 + i) * 16 + qd * 4;
    #pragma unroll
    for (int j = 0; j < 4; ++j) {
      int e = j * 16 + l16;
      float w0 = wl[e * 5], w1 = wl[e * 5 + 1], w2 = wl[e * 5 + 2], w3 = wl[e * 5 + 3], w4 = wl[e * 5 + 4];
      float vv[8];
      #pragma unroll
      for (int m = 0; m < 8; ++m) vv[m] = bf2f(vs[(rl0 + m) * 64 + e]);
      float bb = bl[e];
      #pragma unroll
      for (int r = 0; r < 4; ++r) {
        float dwc = vv[r] * w0 + vv[r + 1] * w1 + vv[r + 2] * w2 + vv[r + 3] * w3 + vv[r + 4] * w4;
        float o = acc[i][j][r] * zl[rl0 + r] + dwc + bb;
        qod[qbase + (size_t)(rl0 + r) * 1024 + e] = f2bf(o);
      }
    }
  }
}

extern "C" void kernel_launch(void* const* d_in, const int* in_sizes, int n_in,
                              void* d_out, int out_size, void* d_ws, size_t ws_size,
                              hipStream_t stream) {
  const float* x      = (const float*)d_in[0];
  const float* gamma  = (const float*)d_in[1];
  const float* beta   = (const float*)d_in[2];
  const float* Wqkv   = (const float*)d_in[3];
  const float* bqkv   = (const float*)d_in[4];
  const float* scalep = (const float*)d_in[5];
  const float* dwcw   = (const float*)d_in[6];
  const float* dwcb   = (const float*)d_in[7];
  const float* Wproj  = (const float*)d_in[8];
  const float* bproj  = (const float*)d_in[9];
  float* out = (float*)d_out;

  float* wsf = (float*)d_ws;
  float* s_sum  = wsf;                     // 1024
  float* s_sq   = wsf + 1024;              // 1024
  float* ksum   = wsf + 2048;              // 8192
  float* bn_a   = wsf + 10240;             // 1024
  float* bn_b   = wsf + 11264;             // 1024
  float* invs   = wsf + 12288;             // 1024
  float* kvpart = wsf + 13312;             // 8*128*4096 f32
  us* kvT = (us*)(wsf + 4207616);          // 128*4096 bf16
  us* wtq = (us*)(wsf + 4469760);          // 3072x1024 bf16
  us* wtp = (us*)(wsf + 6042624);          // 1024x1024 bf16
  us* kq  = (us*)(wsf + 6566912);          // 16384x1024 bf16: k, then q, then o+dwc
  us* vbf = (us*)d_out;                    // v bf16 in low half of d_out
  us* xnb = (us*)d_out + 16777216;         // xn bf16 in high half of d_out
  // ws total ~59.8 MB

  zero_f32<<<40, 256, 0, stream>>>(wsf, 10240);
  bn_stats<<<256, 256, 0, stream>>>(x, s_sum, s_sq);
  bn_finalize<<<1, 1024, 0, stream>>>(s_sum, s_sq, gamma, beta, scalep, bn_a, bn_b, invs);
  xn_to_bf16<<<8192, 256, 0, stream>>>(x, bn_a, bn_b, xnb);
  transpose_f32_bf16<<<dim3(48, 16), 256, 0, stream>>>(Wqkv, wtq, 1024, 3072);
  transpose_f32_bf16<<<dim3(16, 16), 256, 0, stream>>>(Wproj, wtp, 1024, 1024);

  gemm_async<us><<<dim3(8, 128), 256, 0, stream>>>(xnb, wtq + 1024 * 1024, bqkv + 1024, kq, 16384, 1024, 1024);  // k
  focus_kernel<<<16384, 256, 0, stream>>>(kq, invs);                                                              // focus(k)
  gemm_async<us><<<dim3(8, 128), 256, 0, stream>>>(xnb, wtq + 2048 * 1024, bqkv + 2048, vbf, 16384, 1024, 1024); // v
  attn_stats3<<<dim3(8, 16, 8), 256, 0, stream>>>(kq, vbf, ksum, kvpart);
  kv_reduce<<<128, 256, 0, stream>>>(kvpart, kvT);
  gemm_async<us><<<dim3(8, 128), 256, 0, stream>>>(xnb, wtq, bqkv, kq, 16384, 1024, 1024);                       // q (over k)
  focus_kernel<<<16384, 256, 0, stream>>>(kq, invs);                                                              // focus(q)
  attn_o2<<<dim3(16, 16, 8), 256, 0, stream>>>(kq, vbf, ksum, kvT, dwcw, dwcb);                                   // o + dwc, in place
  gemm_async<float><<<dim3(8, 128), 256, 0, stream>>>(kq, wtp, bproj, out, 16384, 1024, 1024);                   // proj
}